// Round 1
// baseline (463.701 us; speedup 1.0000x reference)
//
#include <hip/hip_runtime.h>
#include <hip/hip_bf16.h>
#include <stdint.h>

// AttentiveFP readout: B=2048 graphs x (48 real + 1 virtual) nodes, D=256, H=8, DH=32, 4 steps.
// Structure: real-node rows evolve independently (x' = relu(x@Ws)); virtual/GRU state is the
// only sequential dependency (B x 256). Heavy GEMMs are bf16 MFMA; state math is f32.

#define NEG_SLOPE 0.2f

typedef unsigned short u16;
typedef short s16x8 __attribute__((ext_vector_type(8)));
typedef float f32x4 __attribute__((ext_vector_type(4)));
typedef u16 u16x8 __attribute__((ext_vector_type(8)));

__device__ __forceinline__ u16 f2bf(float f) {
  union { float f; uint32_t u; } v; v.f = f;
  uint32_t r = (v.u + 0x7FFFu + ((v.u >> 16) & 1u)) >> 16;  // RNE
  return (u16)r;
}
__device__ __forceinline__ float bf2f(u16 h) {
  union { uint32_t u; float f; } v; v.u = ((uint32_t)h) << 16;
  return v.f;
}

__device__ __forceinline__ void gload_lds16(const void* g, void* l) {
  __builtin_amdgcn_global_load_lds(
      (const __attribute__((address_space(1))) void*)g,
      (__attribute__((address_space(3))) void*)l, 16, 0, 0);
}

// ---------------------------------------------------------------------------
// Generic bf16 GEMM: C[M,N] = A[M,K=256] * Bt[N,K=256]^T, tiles 128x128, BK=64.
// 256 threads = 4 waves in 2x2 grid, each wave 64x64 via 16x16x32 MFMA.
// LDS layout: two k-halves of [128][32] u16 (64B row stride) so staging stays
// linear for global_load_lds while frag reads avoid the 128B-stride 16-way conflict.
// EPI: 0 = f32 store; 1 = split N=512 -> h bf16 (n<256) | relu->x bf16 (n>=256);
//      2 = f32 + bias (projection).
// ---------------------------------------------------------------------------
template<int EPI>
__global__ __launch_bounds__(256)
void gemm_bt(const u16* __restrict__ A, int lda,
             const u16* __restrict__ Bt,
             float* __restrict__ Cf, int ldc, const float* __restrict__ bias,
             u16* __restrict__ Ch, u16* __restrict__ Cx) {
  __shared__ u16 ldsA[2 * 128 * 32];
  __shared__ u16 ldsB[2 * 128 * 32];
  const int tid = threadIdx.x;
  const int w = tid >> 6;
  const int l = tid & 63;
  const int wr = w >> 1, wc = w & 1;
  const int lr = l & 15, lk = l >> 4;
  const int m0 = blockIdx.x * 128, n0 = blockIdx.y * 128;

  f32x4 acc[4][4];
#pragma unroll
  for (int i = 0; i < 4; ++i)
#pragma unroll
    for (int j = 0; j < 4; ++j) acc[i][j] = (f32x4){0.f, 0.f, 0.f, 0.f};

  for (int kt = 0; kt < 4; ++kt) {
    const u16* Ag = A + (size_t)m0 * lda + kt * 64;
    const u16* Bg = Bt + (size_t)n0 * 256 + kt * 64;
#pragma unroll
    for (int i = 0; i < 4; ++i) {
      int q = i * 256 + tid;                 // chunk id 0..1023, 16B each
      int h2 = q >> 9;                       // k-half
      int r  = (q >> 2) & 127;               // row
      int c4 = q & 3;                        // 16B chunk within 64B half-row
      gload_lds16(Ag + (size_t)r * lda + h2 * 32 + c4 * 8,
                  &ldsA[(i * 256 + w * 64) * 8]);
      gload_lds16(Bg + (size_t)r * 256 + h2 * 32 + c4 * 8,
                  &ldsB[(i * 256 + w * 64) * 8]);
    }
    __syncthreads();  // drains vmcnt(0): staged tiles visible
#pragma unroll
    for (int kk = 0; kk < 64; kk += 32) {
      const int hb = (kk >> 5) * 4096;
      s16x8 af[4], bfr[4];
#pragma unroll
      for (int mi = 0; mi < 4; ++mi)
        af[mi] = *(const s16x8*)&ldsA[hb + (wr * 64 + mi * 16 + lr) * 32 + lk * 8];
#pragma unroll
      for (int ni = 0; ni < 4; ++ni)
        bfr[ni] = *(const s16x8*)&ldsB[hb + (wc * 64 + ni * 16 + lr) * 32 + lk * 8];
#pragma unroll
      for (int mi = 0; mi < 4; ++mi)
#pragma unroll
        for (int ni = 0; ni < 4; ++ni)
          acc[mi][ni] = __builtin_amdgcn_mfma_f32_16x16x32_bf16(af[mi], bfr[ni], acc[mi][ni], 0, 0, 0);
    }
    __syncthreads();  // protect restage
  }

#pragma unroll
  for (int mi = 0; mi < 4; ++mi) {
#pragma unroll
    for (int ni = 0; ni < 4; ++ni) {
      f32x4 v = acc[mi][ni];
      int r = m0 + wr * 64 + mi * 16 + lk * 4;
      int c = n0 + wc * 64 + ni * 16 + lr;
#pragma unroll
      for (int j = 0; j < 4; ++j) {
        float fv = v[j];
        if (EPI == 0) {
          Cf[(size_t)(r + j) * ldc + c] = fv;
        } else if (EPI == 1) {
          if (c < 256) Ch[(size_t)(r + j) * 256 + c] = f2bf(fv);
          else         Cx[(size_t)(r + j) * 256 + (c - 256)] = f2bf(fmaxf(fv, 0.f));
        } else {
          Cf[(size_t)(r + j) * ldc + c] = fv + bias[c];
        }
      }
    }
  }
}

// Transpose-convert f32 [K,N] -> bf16 [N,K]
__global__ void tcvt_kernel(const float* __restrict__ in, u16* __restrict__ out, int K, int N) {
  int idx = blockIdx.x * blockDim.x + threadIdx.x;
  if (idx >= K * N) return;
  int n = idx / K, k = idx - n * K;
  out[idx] = f2bf(in[(size_t)k * N + n]);
}

// x0 bf16 + virtual sum -> state f32 and GS state half (bf16)
__global__ void prep_x_kernel(const float* __restrict__ nf, u16* __restrict__ X0,
                              float* __restrict__ state, u16* __restrict__ GS) {
  int b = blockIdx.x, d = threadIdx.x;
  const float* src = nf + (size_t)b * 48 * 256 + d;
  u16* dst = X0 + (size_t)b * 48 * 256 + d;
  float acc = 0.f;
#pragma unroll 4
  for (int s = 0; s < 48; ++s) {
    float v = src[(size_t)s * 256];
    acc += v;
    dst[(size_t)s * 256] = f2bf(v);
  }
  state[b * 256 + d] = acc;
  GS[(size_t)b * 512 + 256 + d] = f2bf(acc);
}

// Per-graph attention: e_src/e_dst -> leaky -> softmax(s) -> msg -> g0 = relu(msg+sv)
__global__ __launch_bounds__(256)
void attn_kernel(const u16* __restrict__ Hbuf, const float* __restrict__ HVSV,
                 const float* __restrict__ att_src, const float* __restrict__ att_dst,
                 u16* __restrict__ GS) {
  __shared__ u16 hls[48 * 256];
  __shared__ float e[48 * 8];
  __shared__ float edst[8];
  __shared__ float asrc[256];
  const int b = blockIdx.x, tid = threadIdx.x;
  const u16* hg = Hbuf + (size_t)b * 48 * 256;
  for (int i = tid; i < 48 * 256 / 8; i += 256)
    ((u16x8*)hls)[i] = ((const u16x8*)hg)[i];
  asrc[tid] = att_src[tid];
  if (tid < 8) {
    float s = 0.f;
    const float* hv = HVSV + (size_t)b * 512 + tid * 32;
    const float* ad = att_dst + tid * 32;
    for (int d2 = 0; d2 < 32; ++d2) s += hv[d2] * ad[d2];
    edst[tid] = s;
  }
  __syncthreads();
  for (int idx = tid; idx < 48 * 8; idx += 256) {
    int s = idx >> 3, hh = idx & 7;
    float acc = 0.f;
    const u16* hr = &hls[s * 256 + hh * 32];
    for (int d2 = 0; d2 < 32; ++d2) acc += bf2f(hr[d2]) * asrc[hh * 32 + d2];
    float ee = acc + edst[hh];
    e[s * 8 + hh] = (ee > 0.f) ? ee : NEG_SLOPE * ee;
  }
  __syncthreads();
  if (tid < 8) {
    float mx = -1e30f;
    for (int s = 0; s < 48; ++s) mx = fmaxf(mx, e[s * 8 + tid]);
    float sum = 0.f;
    for (int s = 0; s < 48; ++s) { float ex = expf(e[s * 8 + tid] - mx); e[s * 8 + tid] = ex; sum += ex; }
    float inv = 1.f / sum;
    for (int s = 0; s < 48; ++s) e[s * 8 + tid] *= inv;
  }
  __syncthreads();
  const int d = tid, hh = d >> 5;
  float m = 0.f;
  for (int s = 0; s < 48; ++s) m += e[s * 8 + hh] * bf2f(hls[s * 256 + d]);
  float g0 = fmaxf(m + HVSV[(size_t)b * 512 + 256 + d], 0.f);
  GS[(size_t)b * 512 + d] = f2bf(g0);
}

// GRU elementwise from the two gate GEMMs
__global__ void gru_kernel(const float* __restrict__ G1, const float* __restrict__ G2,
                           const float* __restrict__ bx, const float* __restrict__ bh,
                           float* __restrict__ state, u16* __restrict__ GS) {
  const int b = blockIdx.x, d = threadIdx.x;
  const float* g1 = G1 + (size_t)b * 768;
  const float* g2 = G2 + (size_t)b * 768;
  float xz = g1[d] + bx[d], xr = g1[256 + d] + bx[256 + d], xh = g1[512 + d] + bx[512 + d];
  float hz = g2[d] + bh[d], hr = g2[256 + d] + bh[256 + d], hh2 = g2[512 + d] + bh[512 + d];
  float z = 1.f / (1.f + expf(-(xz + hz)));
  float r = 1.f / (1.f + expf(-(xr + hr)));
  float n = tanhf(xh + r * hh2);
  float h0 = state[b * 256 + d];
  float sn = z * h0 + (1.f - z) * n;
  state[b * 256 + d] = sn;
  GS[(size_t)b * 512 + 256 + d] = f2bf(sn);
}

extern "C" void kernel_launch(void* const* d_in, const int* in_sizes, int n_in,
                              void* d_out, int out_size, void* d_ws, size_t ws_size,
                              hipStream_t stream) {
  const float* nf  = (const float*)d_in[0];
  const float* Wg  = (const float*)d_in[2];
  const float* Ws  = (const float*)d_in[3];
  const float* asr = (const float*)d_in[4];
  const float* ads = (const float*)d_in[5];
  const float* wx  = (const float*)d_in[6];
  const float* wh  = (const float*)d_in[7];
  const float* bx  = (const float*)d_in[8];
  const float* bh  = (const float*)d_in[9];
  const float* pw  = (const float*)d_in[10];
  const float* pb  = (const float*)d_in[11];
  float* out = (float*)d_out;

  char* p = (char*)d_ws;
  size_t off = 0;
  auto alloc = [&](size_t bytes) { char* r = p + off; off += (bytes + 255) & ~255ULL; return r; };
  u16* W2T   = (u16*)alloc(512 * 256 * 2);            // [Wg^T ; Ws^T]  (N=512, K=256)
  u16* WXT   = (u16*)alloc(768 * 256 * 2);
  u16* WHT   = (u16*)alloc(768 * 256 * 2);
  u16* PRJ   = (u16*)alloc(256 * 256 * 2);
  u16* X0    = (u16*)alloc((size_t)98304 * 256 * 2);  // real-node features, ping
  u16* X1    = (u16*)alloc((size_t)98304 * 256 * 2);  // pong
  u16* Hb    = (u16*)alloc((size_t)98304 * 256 * 2);  // h (real rows)
  float* HVSV = (float*)alloc((size_t)2048 * 512 * 4); // [hv | sv] per graph
  float* G1   = (float*)alloc((size_t)2048 * 768 * 4);
  float* G2   = (float*)alloc((size_t)2048 * 768 * 4);
  u16* GS     = (u16*)alloc((size_t)2048 * 512 * 2);  // [g0 | state] bf16
  float* ST   = (float*)alloc((size_t)2048 * 256 * 4);

  tcvt_kernel<<<(256 * 256 + 255) / 256, 256, 0, stream>>>(Wg, W2T, 256, 256);
  tcvt_kernel<<<(256 * 256 + 255) / 256, 256, 0, stream>>>(Ws, W2T + 256 * 256, 256, 256);
  tcvt_kernel<<<(256 * 768 + 255) / 256, 256, 0, stream>>>(wx, WXT, 256, 768);
  tcvt_kernel<<<(256 * 768 + 255) / 256, 256, 0, stream>>>(wh, WHT, 256, 768);
  tcvt_kernel<<<(256 * 256 + 255) / 256, 256, 0, stream>>>(pw, PRJ, 256, 256);
  prep_x_kernel<<<2048, 256, 0, stream>>>(nf, X0, ST, GS);

  u16* xc = X0; u16* xn = X1;
  for (int t = 0; t < 4; ++t) {
    // virtual row: hv = state@Wg, sv = state@Ws   (M=2048, N=512)
    gemm_bt<0><<<dim3(16, 4), 256, 0, stream>>>(GS + 256, 512, W2T, HVSV, 512, nullptr, nullptr, nullptr);
    // real rows: h = x@Wg (bf16), xnext = relu(x@Ws) (bf16)  (M=98304, N=512)
    gemm_bt<1><<<dim3(768, 4), 256, 0, stream>>>(xc, 256, W2T, nullptr, 0, nullptr, Hb, xn);
    // attention + g0
    attn_kernel<<<2048, 256, 0, stream>>>(Hb, HVSV, asr, ads, GS);
    // GRU gates
    gemm_bt<0><<<dim3(16, 6), 256, 0, stream>>>(GS, 512, WXT, G1, 768, nullptr, nullptr, nullptr);
    gemm_bt<0><<<dim3(16, 6), 256, 0, stream>>>(GS + 256, 512, WHT, G2, 768, nullptr, nullptr, nullptr);
    gru_kernel<<<2048, 256, 0, stream>>>(G1, G2, bx, bh, ST, GS);
    u16* tmp = xc; xc = xn; xn = tmp;
  }
  // out = state @ proj_w + proj_b  (f32)
  gemm_bt<2><<<dim3(16, 2), 256, 0, stream>>>(GS + 256, 512, PRJ, out, 256, pb, nullptr, nullptr);
}